// Round 7
// baseline (485.095 us; speedup 1.0000x reference)
//
#include <hip/hip_runtime.h>
#include <math.h>

// CropRoi — R6 PROBE: exact R5 algorithm (float4 staging, window table),
// repeated REPS=16x inside one dispatch with per-rep channel rotation
// (ce = (c+rep)&127) so the dispatch exceeds rocprof's top-5 threshold and
// returns counters for THIS structure. Every rep covers all (n,c) pairs;
// output is written REPS times with identical values -> bit-identical result.
//
// f:         (B=2, C=128, 32, 64, 64) float32
// proposals: (N=32, 8) float32 = [b, score, cz, cy, cx, sz, sy, sx]
// out:       (N=32, C=128, 7, 7, 7) float32

constexpr int C_CH = 128;
constexpr int FD = 32, FH = 64, FW = 64;
constexpr int CH_VOL = FD * FH * FW;        // 131072
constexpr int LMAX = 17;
constexpr int XPAD = 20;                    // 17 + up to 3 align shift
constexpr int VQ   = XPAD / 4;              // 5 float4 per row
constexpr int PLQ  = LMAX * VQ;             // 85 float4 per z-plane
constexpr int THREADS = 256;
constexpr int REPS = 16;                    // probe multiplier

__global__ __launch_bounds__(THREADS) void crop_roi_kernel(
    const float* __restrict__ f,
    const float* __restrict__ proposals,
    float* __restrict__ out)
{
    __shared__ __align__(16) float lds[LMAX * LMAX * XPAD];   // 23120 B
    __shared__ int ws_[3][7], we_[3][7];

    const int n = blockIdx.x;               // proposal
    const int c = blockIdx.y;               // base channel

    const float* p = proposals + n * 8;
    const int   b  = (int)p[0];
    const float cz = p[2], cy = p[3], cx = p[4];
    const float sz = p[5], sy = p[6], sx = p[7];

    const int c0z = max((int)floorf((cz - sz * 0.5f) * 0.25f), 0);
    const int c0y = max((int)floorf((cy - sy * 0.5f) * 0.25f), 0);
    const int c0x = max((int)floorf((cx - sx * 0.5f) * 0.25f), 0);
    const int c1z = min((int)ceilf((cz + sz * 0.5f) * 0.25f), FD);
    const int c1y = min((int)ceilf((cy + sy * 0.5f) * 0.25f), FH);
    const int c1x = min((int)ceilf((cx + sx * 0.5f) * 0.25f), FW);
    const int Lz = c1z - c0z, Ly = c1y - c0y, Lx = c1x - c0x;

    if (threadIdx.x < 21) {                 // rep-invariant window table
        const int d = threadIdx.x / 7;
        const int i = threadIdx.x % 7;
        const int L = (d == 0) ? Lz : (d == 1) ? Ly : Lx;
        ws_[d][i] = (i * L) / 7;
        we_[d][i] = ((i + 1) * L + 6) / 7;
    }

    const int ax0   = c0x & ~3;
    const int shift = c0x - ax0;
    const int nvec  = (shift + Lx + 3) >> 2;
    const int tot   = Lz * PLQ;

    for (int rep = 0; rep < REPS; ++rep) {
        const int ce = (c + rep) & (C_CH - 1);   // rotated channel

        const float4* f4 = reinterpret_cast<const float4*>(
            f + (size_t)(b * C_CH + ce) * CH_VOL + c0z * (FH * FW) + c0y * FW + ax0);
        float4* lds4 = reinterpret_cast<float4*>(lds);

        for (int v = threadIdx.x; v < tot; v += THREADS) {
            const int z = v / PLQ;
            const int r = v - z * PLQ;
            const int y = r / VQ;
            const int q = r - y * VQ;
            if (y < Ly && q < nvec) {
                lds4[v] = f4[z * (FH * FW / 4) + y * (FW / 4) + q];
            }
        }
        __syncthreads();

        for (int r = threadIdx.x; r < 343; r += THREADS) {
            const int iz = r / 49, iy = (r / 7) % 7, ix = r % 7;
            const int zs = ws_[0][iz], ze = we_[0][iz];
            const int ys = ws_[1][iy], ye = we_[1][iy];
            const int xs = ws_[2][ix] + shift, xm = we_[2][ix] - 1 + shift;
            const int x1 = min(xs + 1, xm);
            const int x2 = min(xs + 2, xm);
            const int x3 = min(xs + 3, xm);

            float m = -INFINITY;
            for (int z = zs; z < ze; ++z) {
                for (int y = ys; y < ye; ++y) {
                    const float* Lp = lds + (z * LMAX + y) * XPAD;
                    m = fmaxf(m, fmaxf(fmaxf(Lp[xs], Lp[x1]), fmaxf(Lp[x2], Lp[x3])));
                }
            }
            out[(size_t)(n * C_CH + ce) * 343 + r] = m;
        }
        __syncthreads();                    // protect LDS before next restage
    }
}

extern "C" void kernel_launch(void* const* d_in, const int* in_sizes, int n_in,
                              void* d_out, int out_size, void* d_ws, size_t ws_size,
                              hipStream_t stream) {
    const float* f         = (const float*)d_in[0];
    // d_in[1] = `inputs` zeros tensor — shape-only in the reference; unused.
    const float* proposals = (const float*)d_in[2];
    float* out             = (float*)d_out;

    dim3 grid(32, C_CH);     // 32 proposals x 128 channels = 4096 blocks
    crop_roi_kernel<<<grid, THREADS, 0, stream>>>(f, proposals, out);
}

// Round 8
// 210.469 us; speedup vs baseline: 2.3048x; 2.3048x over previous
//
#include <hip/hip_runtime.h>
#include <math.h>

// CropRoi — R7: R5 float4-staging structure + single-round pooling.
// Probe (R6) showed: kernel = 20 µs isolated, VALU-issue-bound (54% busy),
// pooling's 343-over-256 two-round split was the critical path. Fix:
// THREADS=384 -> every output computed in ONE round (1 output/lane),
// staging in 2.4 rounds, occupancy cap 30/32 waves (5 blocks x 6 waves).
// Max-combine written as two triples so LLVM folds to v_max3_f32.
//
// f:         (B=2, C=128, 32, 64, 64) float32
// proposals: (N=32, 8) float32 = [b, score, cz, cy, cx, sz, sy, sx]
// out:       (N=32, C=128, 7, 7, 7) float32
//
// Reference semantics:
//   c0 = max(floor((center - side/2)/4), 0); c1 = min(ceil((center + side/2)/4), dim)
//   L = c1 - c0  (in [4,17] here); window i = [i*L//7, ceil((i+1)*L/7)), width 1..4.
// Staged cells at y>=Ly (clamp rows skipped entirely) are never read by pooling
// since window bounds are strictly < L per dimension.

constexpr int C_CH = 128;
constexpr int FD = 32, FH = 64, FW = 64;
constexpr int CH_VOL = FD * FH * FW;        // 131072
constexpr int LMAX = 17;
constexpr int XPAD = 20;                    // 17 + up to 3 alignment shift
constexpr int VQ   = XPAD / 4;              // 5 float4 per row
constexpr int PLQ  = LMAX * VQ;             // 85 float4 per z-plane
constexpr int THREADS = 384;                // 6 waves; 343 outputs in one round

__global__ __launch_bounds__(THREADS) void crop_roi_kernel(
    const float* __restrict__ f,
    const float* __restrict__ proposals,
    float* __restrict__ out)
{
    __shared__ __align__(16) float lds[LMAX * LMAX * XPAD];   // 23120 B
    __shared__ int ws_[3][7], we_[3][7];

    const int n = blockIdx.x;               // proposal
    const int c = blockIdx.y;               // channel

    const float* p = proposals + n * 8;
    const int   b  = (int)p[0];
    const float cz = p[2], cy = p[3], cx = p[4];
    const float sz = p[5], sy = p[6], sx = p[7];

    const int c0z = max((int)floorf((cz - sz * 0.5f) * 0.25f), 0);
    const int c0y = max((int)floorf((cy - sy * 0.5f) * 0.25f), 0);
    const int c0x = max((int)floorf((cx - sx * 0.5f) * 0.25f), 0);
    const int c1z = min((int)ceilf((cz + sz * 0.5f) * 0.25f), FD);
    const int c1y = min((int)ceilf((cy + sy * 0.5f) * 0.25f), FH);
    const int c1x = min((int)ceilf((cx + sx * 0.5f) * 0.25f), FW);
    const int Lz = c1z - c0z, Ly = c1y - c0y, Lx = c1x - c0x;

    // window-bound table: 21 threads compute, all read via LDS
    if (threadIdx.x < 21) {
        const int d = threadIdx.x / 7;      // 0=z, 1=y, 2=x
        const int i = threadIdx.x % 7;
        const int L = (d == 0) ? Lz : (d == 1) ? Ly : Lx;
        ws_[d][i] = (i * L) / 7;
        we_[d][i] = ((i + 1) * L + 6) / 7;
    }

    // ---- float4 staging (aligned x start; rows y>=Ly skipped) ----
    const int ax0   = c0x & ~3;
    const int shift = c0x - ax0;                  // 0..3
    const int nvec  = (shift + Lx + 3) >> 2;      // float4 chunks per row, <= 5

    const float4* f4 = reinterpret_cast<const float4*>(
        f + (size_t)(b * C_CH + c) * CH_VOL + c0z * (FH * FW) + c0y * FW + ax0);
    float4* lds4 = reinterpret_cast<float4*>(lds);

    const int tot = Lz * PLQ;               // <= 1445 float4 slots
    for (int v = threadIdx.x; v < tot; v += THREADS) {
        const int z = v / PLQ;              // compile-time magic mul
        const int r = v - z * PLQ;
        const int y = r / VQ;               // compile-time magic mul
        const int q = r - y * VQ;
        if (y < Ly && q < nvec) {
            lds4[v] = f4[z * (FH * FW / 4) + y * (FW / 4) + q];
        }
    }
    __syncthreads();

    // ---- pooling: one output per lane, single round ----
    const int r = threadIdx.x;
    if (r < 343) {
        const int iz = r / 49, iy = (r / 7) % 7, ix = r % 7;
        const int zs = ws_[0][iz], ze = we_[0][iz];
        const int ys = ws_[1][iy], ye = we_[1][iy];
        const int xs = ws_[2][ix] + shift, xm = we_[2][ix] - 1 + shift;
        const int x1 = min(xs + 1, xm);     // clamped 4-wide x window
        const int x2 = min(xs + 2, xm);     // (duplicates harmless under max)
        const int x3 = min(xs + 3, xm);

        float m = -INFINITY;
        for (int z = zs; z < ze; ++z) {
            for (int y = ys; y < ye; ++y) {
                const float* Lp = lds + (z * LMAX + y) * XPAD;
                // two triple-max shapes -> v_max3_f32 x2
                const float t = fmaxf(fmaxf(Lp[xs], Lp[x1]), Lp[x2]);
                m = fmaxf(fmaxf(t, Lp[x3]), m);
            }
        }
        out[(size_t)(n * C_CH + c) * 343 + r] = m;
    }
}

extern "C" void kernel_launch(void* const* d_in, const int* in_sizes, int n_in,
                              void* d_out, int out_size, void* d_ws, size_t ws_size,
                              hipStream_t stream) {
    const float* f         = (const float*)d_in[0];
    // d_in[1] = `inputs` zeros tensor — shape-only in the reference; unused.
    const float* proposals = (const float*)d_in[2];
    float* out             = (float*)d_out;

    dim3 grid(32, C_CH);     // 32 proposals x 128 channels = 4096 blocks
    crop_roi_kernel<<<grid, THREADS, 0, stream>>>(f, proposals, out);
}